// Round 4
// baseline (2548.591 us; speedup 1.0000x reference)
//
#include <hip/hip_runtime.h>
#include <hip/hip_bf16.h>

#define N_NODES 100000
#define N_EDGES 3200000
#define F_IN    512
#define H_DIM   64
#define C_DIM   64
#define K_STEPS 10
#define ALPHA   0.1f
#define NB      4
#define BUCKET_DIV 25000
#define NTOT    (NB * N_NODES)
#define NBLK    ((NTOT + 1023) / 1024)

typedef __attribute__((ext_vector_type(8))) short bf16x8;
typedef __attribute__((ext_vector_type(4))) float f32x4;

// ---- bf16 helpers (storage only; all math fp32) ----
__device__ __forceinline__ float bf2f(ushort u) {
    union { unsigned int i; float f; } c; c.i = ((unsigned int)u) << 16; return c.f;
}
__device__ __forceinline__ ushort f2bf(float f) {
    union { float f; unsigned int i; } c; c.f = f;
    unsigned int lsb = (c.i >> 16) & 1u;
    unsigned int r = c.i + 0x7fffu + lsb;   // round to nearest even
    return (ushort)(r >> 16);
}

// ---------------------------------------------------------------- zero deg/cursor
__global__ void zero_kernel(int* __restrict__ degb, int* __restrict__ cursor, int n) {
    int i = blockIdx.x * blockDim.x + threadIdx.x;
    if (i < n) { degb[i] = 0; cursor[i] = 0; }
}

// ---------------------------------------------------------------- per-(bucket,dst) degree
__global__ void degb_kernel(const int* __restrict__ src, const int* __restrict__ dst,
                            int* __restrict__ degb, int e) {
    int i = blockIdx.x * blockDim.x + threadIdx.x;
    if (i < e) {
        int s = src[i];
        atomicAdd(&degb[(s / BUCKET_DIV) * N_NODES + dst[i]], 1);
    }
}

// ---------------------------------------------------------------- dinv (total in-degree + 1)
__global__ void dinv_kernel(const int* __restrict__ degb, float* __restrict__ dinv, int n) {
    int i = blockIdx.x * blockDim.x + threadIdx.x;
    if (i < n) {
        int dg = degb[i] + degb[N_NODES + i] + degb[2 * N_NODES + i] + degb[3 * N_NODES + i];
        dinv[i] = rsqrtf((float)dg + 1.0f);
    }
}

// ---------------------------------------------------------------- hierarchical scan (NTOT entries)
__global__ void blockscan_kernel(const int* __restrict__ in, int* __restrict__ out,
                                 int* __restrict__ bsum, int n) {
    __shared__ int wsum[16];
    int tid = threadIdx.x;
    int lane = tid & 63;
    int w = tid >> 6;
    int i = blockIdx.x * 1024 + tid;
    int v = (i < n) ? in[i] : 0;
    int incl = v;
    #pragma unroll
    for (int off = 1; off < 64; off <<= 1) {
        int t = __shfl_up(incl, off);
        if (lane >= off) incl += t;
    }
    if (lane == 63) wsum[w] = incl;
    __syncthreads();
    int woff = 0;
    #pragma unroll
    for (int j = 0; j < 16; ++j) woff += (j < w) ? wsum[j] : 0;
    if (i < n) out[i] = woff + (incl - v);
    if (tid == 0) {
        int tot = 0;
        #pragma unroll
        for (int j = 0; j < 16; ++j) tot += wsum[j];
        bsum[blockIdx.x] = tot;
    }
}

__global__ void scanpartials_kernel(int* __restrict__ bsum, int nblk) {
    __shared__ int wsum[16];
    int tid = threadIdx.x;
    int lane = tid & 63;
    int w = tid >> 6;
    int v = (tid < nblk) ? bsum[tid] : 0;
    int incl = v;
    #pragma unroll
    for (int off = 1; off < 64; off <<= 1) {
        int t = __shfl_up(incl, off);
        if (lane >= off) incl += t;
    }
    if (lane == 63) wsum[w] = incl;
    __syncthreads();
    int woff = 0;
    #pragma unroll
    for (int j = 0; j < 16; ++j) woff += (j < w) ? wsum[j] : 0;
    if (tid < nblk) bsum[tid] = woff + (incl - v);
}

__global__ void addoff_kernel(int* __restrict__ out, const int* __restrict__ bsum, int n) {
    int i = blockIdx.x * 1024 + threadIdx.x;
    if (i < n) out[i] += bsum[i >> 10];
    if (i == 0) out[n] = N_EDGES;
}

// ---------------------------------------------------------------- bucketed CSR scatter (src only)
__global__ void scatter_kernel(const int* __restrict__ src, const int* __restrict__ dst,
                               const int* __restrict__ row_start, int* __restrict__ cursor,
                               int* __restrict__ esrc, int e) {
    int i = blockIdx.x * blockDim.x + threadIdx.x;
    if (i >= e) return;
    int s = src[i], d = dst[i];
    int key = (s / BUCKET_DIV) * N_NODES + d;
    int pos = row_start[key] + atomicAdd(&cursor[key], 1);
    esrc[pos] = s;
}

// ---------------------------------------------------------------- convert weights to bf16
__global__ void cvt_w_kernel(const float* __restrict__ W1, const float* __restrict__ W2,
                             ushort* __restrict__ w1bf, ushort* __restrict__ w2bf) {
    int i = blockIdx.x * blockDim.x + threadIdx.x;
    if (i < 64 * 512) w1bf[i] = f2bf(W1[i]);
    if (i < 64 * 64)  w2bf[i] = f2bf(W2[i]);
}

// ---------------------------------------------------------------- fused MFMA MLP (unchanged from r3)
__global__ __launch_bounds__(256, 2) void mlp_mfma_kernel(
    const float* __restrict__ x, const ushort* __restrict__ w1bf, const float* __restrict__ b1,
    const ushort* __restrict__ w2bf, const float* __restrict__ b2, ushort* __restrict__ h, int n)
{
    __shared__ ushort w1s[64 * 512];
    __shared__ ushort w2s[64 * 64];
    __shared__ float  b1s[64], b2s[64];

    int t = threadIdx.x;
    #pragma unroll
    for (int i = 0; i < 16; ++i) {
        int chunk = i * 256 + t;
        int byte = chunk * 16;
        int row = byte >> 10;
        int dst = byte ^ ((row & 7) << 4);
        *reinterpret_cast<uint4*>((char*)w1s + dst) = reinterpret_cast<const uint4*>(w1bf)[chunk];
    }
    #pragma unroll
    for (int i = 0; i < 2; ++i) {
        int chunk = i * 256 + t;
        int byte = chunk * 16;
        int row = byte >> 7;
        int dst = byte ^ ((row & 7) << 4);
        *reinterpret_cast<uint4*>((char*)w2s + dst) = reinterpret_cast<const uint4*>(w2bf)[chunk];
    }
    if (t < 64) { b1s[t] = b1[t]; b2s[t] = b2[t]; }
    __syncthreads();

    int wid = t >> 6;
    int l   = t & 63;
    int lr  = l & 15;
    int lk  = l >> 4;
    int rowbase = blockIdx.x * 256 + wid * 64;

    f32x4 acc[4][4] = {};
    for (int kk = 0; kk < 16; ++kk) {
        int k0 = kk * 32 + lk * 8;
        bf16x8 a[4];
        #pragma unroll
        for (int fr = 0; fr < 4; ++fr) {
            int row = rowbase + fr * 16 + lr;
            row = (row < n) ? row : (n - 1);
            const float* p = x + (size_t)row * F_IN + k0;
            float4 u0 = *reinterpret_cast<const float4*>(p);
            float4 u1 = *reinterpret_cast<const float4*>(p + 4);
            bf16x8 af;
            af[0] = (short)f2bf(u0.x); af[1] = (short)f2bf(u0.y);
            af[2] = (short)f2bf(u0.z); af[3] = (short)f2bf(u0.w);
            af[4] = (short)f2bf(u1.x); af[5] = (short)f2bf(u1.y);
            af[6] = (short)f2bf(u1.z); af[7] = (short)f2bf(u1.w);
            a[fr] = af;
        }
        bf16x8 b[4];
        #pragma unroll
        for (int fc = 0; fc < 4; ++fc) {
            int nn = fc * 16 + lr;
            int byte = nn * 1024 + k0 * 2;
            b[fc] = *reinterpret_cast<const bf16x8*>((char*)w1s + (byte ^ ((nn & 7) << 4)));
        }
        #pragma unroll
        for (int fr = 0; fr < 4; ++fr)
            #pragma unroll
            for (int fc = 0; fc < 4; ++fc)
                acc[fr][fc] = __builtin_amdgcn_mfma_f32_16x16x32_bf16(a[fr], b[fc], acc[fr][fc], 0, 0, 0);
    }

    __syncthreads();
    ushort* h1w = w1s + wid * 4096;
    #pragma unroll
    for (int fr = 0; fr < 4; ++fr) {
        #pragma unroll
        for (int fc = 0; fc < 4; ++fc) {
            #pragma unroll
            for (int reg = 0; reg < 4; ++reg) {
                float v = acc[fr][fc][reg] + b1s[fc * 16 + lr];
                v = fmaxf(v, 0.f);
                int row = fr * 16 + lk * 4 + reg;
                int col = fc * 16 + lr;
                int byte = row * 128 + col * 2;
                *reinterpret_cast<ushort*>((char*)h1w + (byte ^ ((row & 7) << 4))) = f2bf(v);
            }
        }
    }

    f32x4 acc2[4][4] = {};
    #pragma unroll
    for (int kk = 0; kk < 2; ++kk) {
        int k0 = kk * 32 + lk * 8;
        bf16x8 a2[4], bb[4];
        #pragma unroll
        for (int fr = 0; fr < 4; ++fr) {
            int row = fr * 16 + lr;
            int byte = row * 128 + k0 * 2;
            a2[fr] = *reinterpret_cast<const bf16x8*>((char*)h1w + (byte ^ ((row & 7) << 4)));
        }
        #pragma unroll
        for (int fc = 0; fc < 4; ++fc) {
            int nn = fc * 16 + lr;
            int byte = nn * 128 + k0 * 2;
            bb[fc] = *reinterpret_cast<const bf16x8*>((char*)w2s + (byte ^ ((nn & 7) << 4)));
        }
        #pragma unroll
        for (int fr = 0; fr < 4; ++fr)
            #pragma unroll
            for (int fc = 0; fc < 4; ++fc)
                acc2[fr][fc] = __builtin_amdgcn_mfma_f32_16x16x32_bf16(a2[fr], bb[fc], acc2[fr][fc], 0, 0, 0);
    }

    #pragma unroll
    for (int fr = 0; fr < 4; ++fr) {
        #pragma unroll
        for (int fc = 0; fc < 4; ++fc) {
            #pragma unroll
            for (int reg = 0; reg < 4; ++reg) {
                int row = rowbase + fr * 16 + lk * 4 + reg;
                int col = fc * 16 + lr;
                if (row < n)
                    h[(size_t)row * C_DIM + col] = f2bf(acc2[fr][fc][reg] + b2s[col]);
            }
        }
    }
}

// ---------------------------------------------------------------- APPNP bucket pass
// MODE 0: acc = bucket_sum + selfw*z_in   (first bucket)
// MODE 1: acc += bucket_sum               (middle buckets)
// MODE 2: z_out = (1-a)*(acc+bucket_sum) + a*h  (last bucket)
// MODE 3: like 2 but fused log_softmax -> fp32 out (final step)
template<int MODE>
__global__ __launch_bounds__(256) void appnp_pass_kernel(
    const int* __restrict__ rs, const int* __restrict__ esrc,
    const float* __restrict__ dinv, const ushort* __restrict__ zin,
    const ushort* __restrict__ h, float* __restrict__ acc,
    ushort* __restrict__ zout, float* __restrict__ lsm, int n)
{
    int idx = blockIdx.x * blockDim.x + threadIdx.x;
    int wid = idx >> 6;
    int lane = idx & 63;
    if (wid >= n) return;
    int beg = rs[wid];
    int end = rs[wid + 1];
    float a0 = 0.f, a1 = 0.f, a2 = 0.f, a3 = 0.f;
    int e = beg;
    for (; e + 3 < end; e += 4) {
        int s0 = esrc[e], s1 = esrc[e + 1], s2 = esrc[e + 2], s3 = esrc[e + 3];
        float w0 = dinv[s0], w1 = dinv[s1], w2 = dinv[s2], w3 = dinv[s3];
        a0 = fmaf(w0, bf2f(zin[(size_t)s0 * 64 + lane]), a0);
        a1 = fmaf(w1, bf2f(zin[(size_t)s1 * 64 + lane]), a1);
        a2 = fmaf(w2, bf2f(zin[(size_t)s2 * 64 + lane]), a2);
        a3 = fmaf(w3, bf2f(zin[(size_t)s3 * 64 + lane]), a3);
    }
    for (; e < end; ++e) {
        int s = esrc[e];
        a0 = fmaf(dinv[s], bf2f(zin[(size_t)s * 64 + lane]), a0);
    }
    float dd = dinv[wid];
    float sum = ((a0 + a1) + (a2 + a3)) * dd;   // dinv[dst] factored out
    size_t o = (size_t)wid * 64 + lane;
    if (MODE == 0) {
        float self = dd * dd * bf2f(zin[o]);
        __builtin_nontemporal_store(sum + self, &acc[o]);
    } else if (MODE == 1) {
        float p = __builtin_nontemporal_load(&acc[o]);
        __builtin_nontemporal_store(p + sum, &acc[o]);
    } else if (MODE == 2) {
        float p = __builtin_nontemporal_load(&acc[o]);
        float z = (1.0f - ALPHA) * (p + sum) + ALPHA * bf2f(h[o]);
        __builtin_nontemporal_store(f2bf(z), &zout[o]);
    } else {
        float p = __builtin_nontemporal_load(&acc[o]);
        float z = (1.0f - ALPHA) * (p + sum) + ALPHA * bf2f(h[o]);
        float m = z;
        #pragma unroll
        for (int off = 32; off > 0; off >>= 1) m = fmaxf(m, __shfl_xor(m, off));
        float ex = expf(z - m);
        float ssum = ex;
        #pragma unroll
        for (int off = 32; off > 0; off >>= 1) ssum += __shfl_xor(ssum, off);
        lsm[o] = z - m - logf(ssum);
    }
}

// ---------------------------------------------------------------- launch
extern "C" void kernel_launch(void* const* d_in, const int* in_sizes, int n_in,
                              void* d_out, int out_size, void* d_ws, size_t ws_size,
                              hipStream_t stream) {
    const float* x  = (const float*)d_in[0];
    const float* W1 = (const float*)d_in[1];
    const float* b1 = (const float*)d_in[2];
    const float* W2 = (const float*)d_in[3];
    const float* b2 = (const float*)d_in[4];
    const int*   ei = (const int*)d_in[5];
    const int* src = ei;
    const int* dst = ei + N_EDGES;
    float* out = (float*)d_out;

    char* ws = (char*)d_ws;
    size_t off = 0;
    auto alloc = [&](size_t bytes) -> void* {
        void* p = ws + off;
        off += (bytes + 255) & ~(size_t)255;
        return p;
    };
    int*    degb      = (int*)   alloc((size_t)NTOT * 4);
    int*    cursor    = (int*)   alloc((size_t)NTOT * 4);
    int*    row_start = (int*)   alloc((size_t)(NTOT + 1) * 4);
    int*    bsum      = (int*)   alloc((size_t)NBLK * 4);
    float*  dinv      = (float*) alloc((size_t)N_NODES * 4);
    int*    esrc      = (int*)   alloc((size_t)N_EDGES * 4);
    float*  acc       = (float*) alloc((size_t)N_NODES * C_DIM * 4);
    ushort* h         = (ushort*)alloc((size_t)N_NODES * C_DIM * 2);
    ushort* za        = (ushort*)alloc((size_t)N_NODES * C_DIM * 2);
    ushort* zb        = (ushort*)alloc((size_t)N_NODES * C_DIM * 2);
    ushort* w1bf      = (ushort*)alloc((size_t)H_DIM * F_IN * 2);
    ushort* w2bf      = (ushort*)alloc((size_t)C_DIM * H_DIM * 2);

    zero_kernel<<<(NTOT + 255) / 256, 256, 0, stream>>>(degb, cursor, NTOT);
    degb_kernel<<<(N_EDGES + 255) / 256, 256, 0, stream>>>(src, dst, degb, N_EDGES);
    dinv_kernel<<<(N_NODES + 255) / 256, 256, 0, stream>>>(degb, dinv, N_NODES);
    blockscan_kernel<<<NBLK, 1024, 0, stream>>>(degb, row_start, bsum, NTOT);
    scanpartials_kernel<<<1, 1024, 0, stream>>>(bsum, NBLK);
    addoff_kernel<<<NBLK, 1024, 0, stream>>>(row_start, bsum, NTOT);
    scatter_kernel<<<(N_EDGES + 255) / 256, 256, 0, stream>>>(src, dst, row_start, cursor,
                                                              esrc, N_EDGES);
    cvt_w_kernel<<<(H_DIM * F_IN + 255) / 256, 256, 0, stream>>>(W1, W2, w1bf, w2bf);
    mlp_mfma_kernel<<<(N_NODES + 255) / 256, 256, 0, stream>>>(x, w1bf, b1, w2bf, b2, h, N_NODES);

    const int grid = (N_NODES * 64 + 255) / 256;
    const ushort* zin = h;
    ushort* zout = za;
    for (int k = 0; k < K_STEPS; ++k) {
        appnp_pass_kernel<0><<<grid, 256, 0, stream>>>(row_start + 0 * N_NODES, esrc, dinv,
                                                       zin, h, acc, nullptr, nullptr, N_NODES);
        appnp_pass_kernel<1><<<grid, 256, 0, stream>>>(row_start + 1 * N_NODES, esrc, dinv,
                                                       zin, h, acc, nullptr, nullptr, N_NODES);
        appnp_pass_kernel<1><<<grid, 256, 0, stream>>>(row_start + 2 * N_NODES, esrc, dinv,
                                                       zin, h, acc, nullptr, nullptr, N_NODES);
        if (k < K_STEPS - 1) {
            appnp_pass_kernel<2><<<grid, 256, 0, stream>>>(row_start + 3 * N_NODES, esrc, dinv,
                                                           zin, h, acc, zout, nullptr, N_NODES);
            zin = zout;
            zout = (zout == za) ? zb : za;
        } else {
            appnp_pass_kernel<3><<<grid, 256, 0, stream>>>(row_start + 3 * N_NODES, esrc, dinv,
                                                           zin, h, acc, nullptr, out, N_NODES);
        }
    }
}

// Round 5
// 1827.982 us; speedup vs baseline: 1.3942x; 1.3942x over previous
//
#include <hip/hip_runtime.h>
#include <hip/hip_bf16.h>

#define N_NODES 100000
#define N_EDGES 3200000
#define F_IN    512
#define H_DIM   64
#define C_DIM   64
#define K_STEPS 10
#define ALPHA   0.1f
#define NBLK    ((N_NODES + 1023) / 1024)
#define PLANE   ((size_t)N_NODES * 32)

typedef __attribute__((ext_vector_type(8))) short bf16x8;
typedef __attribute__((ext_vector_type(4))) float f32x4;

// ---- bf16 helpers (storage only; all math fp32) ----
__device__ __forceinline__ float bf2f(ushort u) {
    union { unsigned int i; float f; } c; c.i = ((unsigned int)u) << 16; return c.f;
}
__device__ __forceinline__ ushort f2bf(float f) {
    union { float f; unsigned int i; } c; c.f = f;
    unsigned int lsb = (c.i >> 16) & 1u;
    unsigned int r = c.i + 0x7fffu + lsb;   // round to nearest even
    return (ushort)(r >> 16);
}

// ---------------------------------------------------------------- zero deg/cursor
__global__ void zero_kernel(int* __restrict__ deg, int* __restrict__ cursor, int n) {
    int i = blockIdx.x * blockDim.x + threadIdx.x;
    if (i < n) { deg[i] = 0; cursor[i] = 0; }
}

// ---------------------------------------------------------------- in-degree by dst
__global__ void deg_kernel(const int* __restrict__ dst, int* __restrict__ deg, int e) {
    int i = blockIdx.x * blockDim.x + threadIdx.x;
    if (i < e) atomicAdd(&deg[dst[i]], 1);
}

// ---------------------------------------------------------------- dinv
__global__ void dinv_kernel(const int* __restrict__ deg, float* __restrict__ dinv, int n) {
    int i = blockIdx.x * blockDim.x + threadIdx.x;
    if (i < n) dinv[i] = rsqrtf((float)deg[i] + 1.0f);
}

// ---------------------------------------------------------------- hierarchical exclusive scan
__global__ void blockscan_kernel(const int* __restrict__ in, int* __restrict__ out,
                                 int* __restrict__ bsum, int n) {
    __shared__ int wsum[16];
    int tid = threadIdx.x;
    int lane = tid & 63;
    int w = tid >> 6;
    int i = blockIdx.x * 1024 + tid;
    int v = (i < n) ? in[i] : 0;
    int incl = v;
    #pragma unroll
    for (int off = 1; off < 64; off <<= 1) {
        int t = __shfl_up(incl, off);
        if (lane >= off) incl += t;
    }
    if (lane == 63) wsum[w] = incl;
    __syncthreads();
    int woff = 0;
    #pragma unroll
    for (int j = 0; j < 16; ++j) woff += (j < w) ? wsum[j] : 0;
    if (i < n) out[i] = woff + (incl - v);
    if (tid == 0) {
        int tot = 0;
        #pragma unroll
        for (int j = 0; j < 16; ++j) tot += wsum[j];
        bsum[blockIdx.x] = tot;
    }
}

__global__ void scanpartials_kernel(int* __restrict__ bsum, int nblk) {
    __shared__ int wsum[16];
    int tid = threadIdx.x;
    int lane = tid & 63;
    int w = tid >> 6;
    int v = (tid < nblk) ? bsum[tid] : 0;
    int incl = v;
    #pragma unroll
    for (int off = 1; off < 64; off <<= 1) {
        int t = __shfl_up(incl, off);
        if (lane >= off) incl += t;
    }
    if (lane == 63) wsum[w] = incl;
    __syncthreads();
    int woff = 0;
    #pragma unroll
    for (int j = 0; j < 16; ++j) woff += (j < w) ? wsum[j] : 0;
    if (tid < nblk) bsum[tid] = woff + (incl - v);
}

__global__ void addoff_kernel(int* __restrict__ out, const int* __restrict__ bsum, int n) {
    int i = blockIdx.x * 1024 + threadIdx.x;
    if (i < n) out[i] += bsum[i >> 10];
    if (i == 0) out[n] = N_EDGES;
}

// ---------------------------------------------------------------- CSR scatter (src only, nt store)
__global__ void scatter_kernel(const int* __restrict__ src, const int* __restrict__ dst,
                               const int* __restrict__ row_start, int* __restrict__ cursor,
                               int* __restrict__ esrc, int e) {
    int i = blockIdx.x * blockDim.x + threadIdx.x;
    if (i >= e) return;
    int s = src[i], d = dst[i];
    int pos = row_start[d] + atomicAdd(&cursor[d], 1);
    __builtin_nontemporal_store(s, &esrc[pos]);
}

// ---------------------------------------------------------------- convert weights to bf16
__global__ void cvt_w_kernel(const float* __restrict__ W1, const float* __restrict__ W2,
                             ushort* __restrict__ w1bf, ushort* __restrict__ w2bf) {
    int i = blockIdx.x * blockDim.x + threadIdx.x;
    if (i < 64 * 512) w1bf[i] = f2bf(W1[i]);
    if (i < 64 * 64)  w2bf[i] = f2bf(W2[i]);
}

// ---------------------------------------------------------------- fused MFMA MLP -> h planes
__global__ __launch_bounds__(256, 2) void mlp_mfma_kernel(
    const float* __restrict__ x, const ushort* __restrict__ w1bf, const float* __restrict__ b1,
    const ushort* __restrict__ w2bf, const float* __restrict__ b2, ushort* __restrict__ hp, int n)
{
    __shared__ ushort w1s[64 * 512];
    __shared__ ushort w2s[64 * 64];
    __shared__ float  b1s[64], b2s[64];

    int t = threadIdx.x;
    #pragma unroll
    for (int i = 0; i < 16; ++i) {
        int chunk = i * 256 + t;
        int byte = chunk * 16;
        int row = byte >> 10;
        int dst = byte ^ ((row & 7) << 4);
        *reinterpret_cast<uint4*>((char*)w1s + dst) = reinterpret_cast<const uint4*>(w1bf)[chunk];
    }
    #pragma unroll
    for (int i = 0; i < 2; ++i) {
        int chunk = i * 256 + t;
        int byte = chunk * 16;
        int row = byte >> 7;
        int dst = byte ^ ((row & 7) << 4);
        *reinterpret_cast<uint4*>((char*)w2s + dst) = reinterpret_cast<const uint4*>(w2bf)[chunk];
    }
    if (t < 64) { b1s[t] = b1[t]; b2s[t] = b2[t]; }
    __syncthreads();

    int wid = t >> 6;
    int l   = t & 63;
    int lr  = l & 15;
    int lk  = l >> 4;
    int rowbase = blockIdx.x * 256 + wid * 64;

    f32x4 acc[4][4] = {};
    for (int kk = 0; kk < 16; ++kk) {
        int k0 = kk * 32 + lk * 8;
        bf16x8 a[4];
        #pragma unroll
        for (int fr = 0; fr < 4; ++fr) {
            int row = rowbase + fr * 16 + lr;
            row = (row < n) ? row : (n - 1);
            const float* p = x + (size_t)row * F_IN + k0;
            float4 u0 = *reinterpret_cast<const float4*>(p);
            float4 u1 = *reinterpret_cast<const float4*>(p + 4);
            bf16x8 af;
            af[0] = (short)f2bf(u0.x); af[1] = (short)f2bf(u0.y);
            af[2] = (short)f2bf(u0.z); af[3] = (short)f2bf(u0.w);
            af[4] = (short)f2bf(u1.x); af[5] = (short)f2bf(u1.y);
            af[6] = (short)f2bf(u1.z); af[7] = (short)f2bf(u1.w);
            a[fr] = af;
        }
        bf16x8 b[4];
        #pragma unroll
        for (int fc = 0; fc < 4; ++fc) {
            int nn = fc * 16 + lr;
            int byte = nn * 1024 + k0 * 2;
            b[fc] = *reinterpret_cast<const bf16x8*>((char*)w1s + (byte ^ ((nn & 7) << 4)));
        }
        #pragma unroll
        for (int fr = 0; fr < 4; ++fr)
            #pragma unroll
            for (int fc = 0; fc < 4; ++fc)
                acc[fr][fc] = __builtin_amdgcn_mfma_f32_16x16x32_bf16(a[fr], b[fc], acc[fr][fc], 0, 0, 0);
    }

    __syncthreads();
    ushort* h1w = w1s + wid * 4096;
    #pragma unroll
    for (int fr = 0; fr < 4; ++fr) {
        #pragma unroll
        for (int fc = 0; fc < 4; ++fc) {
            #pragma unroll
            for (int reg = 0; reg < 4; ++reg) {
                float v = acc[fr][fc][reg] + b1s[fc * 16 + lr];
                v = fmaxf(v, 0.f);
                int row = fr * 16 + lk * 4 + reg;
                int col = fc * 16 + lr;
                int byte = row * 128 + col * 2;
                *reinterpret_cast<ushort*>((char*)h1w + (byte ^ ((row & 7) << 4))) = f2bf(v);
            }
        }
    }

    f32x4 acc2[4][4] = {};
    #pragma unroll
    for (int kk = 0; kk < 2; ++kk) {
        int k0 = kk * 32 + lk * 8;
        bf16x8 a2[4], bb[4];
        #pragma unroll
        for (int fr = 0; fr < 4; ++fr) {
            int row = fr * 16 + lr;
            int byte = row * 128 + k0 * 2;
            a2[fr] = *reinterpret_cast<const bf16x8*>((char*)h1w + (byte ^ ((row & 7) << 4)));
        }
        #pragma unroll
        for (int fc = 0; fc < 4; ++fc) {
            int nn = fc * 16 + lr;
            int byte = nn * 128 + k0 * 2;
            bb[fc] = *reinterpret_cast<const bf16x8*>((char*)w2s + (byte ^ ((nn & 7) << 4)));
        }
        #pragma unroll
        for (int fr = 0; fr < 4; ++fr)
            #pragma unroll
            for (int fc = 0; fc < 4; ++fc)
                acc2[fr][fc] = __builtin_amdgcn_mfma_f32_16x16x32_bf16(a2[fr], bb[fc], acc2[fr][fc], 0, 0, 0);
    }

    // epilogue: + b2, write split bf16 planes: hp[(col>>5)*PLANE + row*32 + (col&31)]
    #pragma unroll
    for (int fr = 0; fr < 4; ++fr) {
        #pragma unroll
        for (int fc = 0; fc < 4; ++fc) {
            #pragma unroll
            for (int reg = 0; reg < 4; ++reg) {
                int row = rowbase + fr * 16 + lk * 4 + reg;
                int col = fc * 16 + lr;
                if (row < n)
                    hp[(size_t)(col >> 5) * PLANE + (size_t)row * 32 + (col & 31)] =
                        f2bf(acc2[fr][fc][reg] + b2s[col]);
            }
        }
    }
}

// ---------------------------------------------------------------- init: y0 = dinv*h, g = 0.1*dinv*h, selfc = 0.9*dinv^2
__global__ void init_y_kernel(const ushort* __restrict__ hp, const float* __restrict__ dinv,
                              ushort* __restrict__ y0, ushort* __restrict__ g,
                              float* __restrict__ selfc, int n) {
    int t = blockIdx.x * blockDim.x + threadIdx.x;
    if (t >= n * 64) return;
    int node = t >> 6;
    int c64 = t & 63;
    size_t o = (size_t)(c64 >> 5) * PLANE + (size_t)node * 32 + (c64 & 31);
    float d = dinv[node];
    float hv = bf2f(hp[o]);
    y0[o] = f2bf(d * hv);
    g[o]  = f2bf(ALPHA * d * hv);
    if (c64 == 0) selfc[node] = (1.0f - ALPHA) * d * d;
}

// ---------------------------------------------------------------- APPNP step, one 32-ch plane
// wave = 1 node; lanes = 2 edges x 32 channels. y' = selfc*(sum + y) + g
__global__ __launch_bounds__(256) void appnp_step_kernel(
    const int* __restrict__ rs, const int* __restrict__ esrc,
    const float* __restrict__ selfc, const ushort* __restrict__ yin,
    const ushort* __restrict__ g, ushort* __restrict__ yout, int n)
{
    int idx = blockIdx.x * blockDim.x + threadIdx.x;
    int wid = idx >> 6;
    if (wid >= n) return;
    int lane = threadIdx.x & 63;
    int half = lane >> 5;
    int ch = lane & 31;
    int beg = rs[wid], end = rs[wid + 1];

    float a0 = 0.f, a1 = 0.f, a2 = 0.f, a3 = 0.f;
    int e = beg;
    for (; e + 7 < end; e += 8) {
        int s0 = esrc[e + half];
        int s1 = esrc[e + 2 + half];
        int s2 = esrc[e + 4 + half];
        int s3 = esrc[e + 6 + half];
        a0 += bf2f(yin[(size_t)s0 * 32 + ch]);
        a1 += bf2f(yin[(size_t)s1 * 32 + ch]);
        a2 += bf2f(yin[(size_t)s2 * 32 + ch]);
        a3 += bf2f(yin[(size_t)s3 * 32 + ch]);
    }
    for (; e < end; e += 2) {
        int ee = e + half;
        bool valid = ee < end;
        int s = esrc[valid ? ee : (end - 1)];
        float v = bf2f(yin[(size_t)s * 32 + ch]);
        a0 += valid ? v : 0.f;
    }
    float acc = (a0 + a1) + (a2 + a3);
    acc += __shfl_xor(acc, 32);
    if (half == 0) {
        size_t o = (size_t)wid * 32 + ch;
        float yi = bf2f(yin[o]);
        float yn = selfc[wid] * (acc + yi) + bf2f(g[o]);
        yout[o] = f2bf(yn);
    }
}

// ---------------------------------------------------------------- log_softmax from y planes (z = y/dinv)
__global__ __launch_bounds__(256) void lsm_kernel(const ushort* __restrict__ y,
                                                  const float* __restrict__ dinv,
                                                  float* __restrict__ out, int n) {
    int idx = blockIdx.x * blockDim.x + threadIdx.x;
    int wid = idx >> 6;
    int lane = idx & 63;
    if (wid >= n) return;
    size_t o = (size_t)(lane >> 5) * PLANE + (size_t)wid * 32 + (lane & 31);
    float z = bf2f(y[o]) / dinv[wid];
    float m = z;
    #pragma unroll
    for (int off = 32; off > 0; off >>= 1) m = fmaxf(m, __shfl_xor(m, off));
    float ex = expf(z - m);
    float s = ex;
    #pragma unroll
    for (int off = 32; off > 0; off >>= 1) s += __shfl_xor(s, off);
    out[(size_t)wid * 64 + lane] = z - m - logf(s);
}

// ---------------------------------------------------------------- launch
extern "C" void kernel_launch(void* const* d_in, const int* in_sizes, int n_in,
                              void* d_out, int out_size, void* d_ws, size_t ws_size,
                              hipStream_t stream) {
    const float* x  = (const float*)d_in[0];
    const float* W1 = (const float*)d_in[1];
    const float* b1 = (const float*)d_in[2];
    const float* W2 = (const float*)d_in[3];
    const float* b2 = (const float*)d_in[4];
    const int*   ei = (const int*)d_in[5];
    const int* src = ei;
    const int* dst = ei + N_EDGES;
    float* out = (float*)d_out;

    char* ws = (char*)d_ws;
    size_t off = 0;
    auto alloc = [&](size_t bytes) -> void* {
        void* p = ws + off;
        off += (bytes + 255) & ~(size_t)255;
        return p;
    };
    int*    deg       = (int*)   alloc((size_t)N_NODES * 4);
    int*    cursor    = (int*)   alloc((size_t)N_NODES * 4);
    int*    row_start = (int*)   alloc((size_t)(N_NODES + 1) * 4);
    int*    bsum      = (int*)   alloc((size_t)NBLK * 4);
    float*  dinv      = (float*) alloc((size_t)N_NODES * 4);
    float*  selfc     = (float*) alloc((size_t)N_NODES * 4);
    int*    esrc      = (int*)   alloc((size_t)N_EDGES * 4);
    ushort* hp        = (ushort*)alloc(2 * PLANE * 2);
    ushort* g         = (ushort*)alloc(2 * PLANE * 2);
    ushort* ya        = (ushort*)alloc(2 * PLANE * 2);
    ushort* yb        = (ushort*)alloc(2 * PLANE * 2);
    ushort* w1bf      = (ushort*)alloc((size_t)H_DIM * F_IN * 2);
    ushort* w2bf      = (ushort*)alloc((size_t)C_DIM * H_DIM * 2);

    zero_kernel<<<(N_NODES + 255) / 256, 256, 0, stream>>>(deg, cursor, N_NODES);
    deg_kernel<<<(N_EDGES + 255) / 256, 256, 0, stream>>>(dst, deg, N_EDGES);
    dinv_kernel<<<(N_NODES + 255) / 256, 256, 0, stream>>>(deg, dinv, N_NODES);
    blockscan_kernel<<<NBLK, 1024, 0, stream>>>(deg, row_start, bsum, N_NODES);
    scanpartials_kernel<<<1, 1024, 0, stream>>>(bsum, NBLK);
    addoff_kernel<<<NBLK, 1024, 0, stream>>>(row_start, bsum, N_NODES);
    scatter_kernel<<<(N_EDGES + 255) / 256, 256, 0, stream>>>(src, dst, row_start, cursor,
                                                              esrc, N_EDGES);
    cvt_w_kernel<<<(H_DIM * F_IN + 255) / 256, 256, 0, stream>>>(W1, W2, w1bf, w2bf);
    mlp_mfma_kernel<<<(N_NODES + 255) / 256, 256, 0, stream>>>(x, w1bf, b1, w2bf, b2, hp, N_NODES);
    init_y_kernel<<<(N_NODES * 64 + 255) / 256, 256, 0, stream>>>(hp, dinv, ya, g, selfc, N_NODES);

    const int grid = (N_NODES * 64 + 255) / 256;
    ushort* yin = ya;
    ushort* yout = yb;
    for (int k = 0; k < K_STEPS; ++k) {
        for (int p = 0; p < 2; ++p) {
            appnp_step_kernel<<<grid, 256, 0, stream>>>(
                row_start, esrc, selfc, yin + p * PLANE, g + p * PLANE, yout + p * PLANE, N_NODES);
        }
        ushort* tmp = yin; yin = yout; yout = tmp;
    }
    lsm_kernel<<<grid, 256, 0, stream>>>(yin, dinv, out, N_NODES);
}

// Round 6
// 1207.864 us; speedup vs baseline: 2.1100x; 1.5134x over previous
//
#include <hip/hip_runtime.h>
#include <hip/hip_bf16.h>

#define N_NODES 100000
#define N_EDGES 3200000
#define F_IN    512
#define H_DIM   64
#define C_DIM   64
#define K_STEPS 10
#define ALPHA   0.1f
#define NBLK    ((N_NODES + 1023) / 1024)

typedef __attribute__((ext_vector_type(8))) short bf16x8;
typedef __attribute__((ext_vector_type(4))) float f32x4;

// ---- bf16 helpers (storage only; all math fp32) ----
__device__ __forceinline__ float bf2f(ushort u) {
    union { unsigned int i; float f; } c; c.i = ((unsigned int)u) << 16; return c.f;
}
__device__ __forceinline__ ushort f2bf(float f) {
    union { float f; unsigned int i; } c; c.f = f;
    unsigned int lsb = (c.i >> 16) & 1u;
    unsigned int r = c.i + 0x7fffu + lsb;   // round to nearest even
    return (ushort)(r >> 16);
}

// ---------------------------------------------------------------- zero deg
__global__ void zero_kernel(int* __restrict__ deg, int n) {
    int i = blockIdx.x * blockDim.x + threadIdx.x;
    if (i < n) deg[i] = 0;
}

// ---------------------------------------------------------------- in-degree + per-edge position
__global__ void degpos_kernel(const int* __restrict__ dst, int* __restrict__ deg,
                              int* __restrict__ pos, int e) {
    int i = blockIdx.x * blockDim.x + threadIdx.x;
    if (i < e) pos[i] = atomicAdd(&deg[dst[i]], 1);
}

// ---------------------------------------------------------------- dinv + selfc
__global__ void dinv_kernel(const int* __restrict__ deg, float* __restrict__ dinv,
                            float* __restrict__ selfc, int n) {
    int i = blockIdx.x * blockDim.x + threadIdx.x;
    if (i < n) {
        float d = rsqrtf((float)deg[i] + 1.0f);
        dinv[i]  = d;
        selfc[i] = (1.0f - ALPHA) * d * d;
    }
}

// ---------------------------------------------------------------- hierarchical exclusive scan
__global__ void blockscan_kernel(const int* __restrict__ in, int* __restrict__ out,
                                 int* __restrict__ bsum, int n) {
    __shared__ int wsum[16];
    int tid = threadIdx.x;
    int lane = tid & 63;
    int w = tid >> 6;
    int i = blockIdx.x * 1024 + tid;
    int v = (i < n) ? in[i] : 0;
    int incl = v;
    #pragma unroll
    for (int off = 1; off < 64; off <<= 1) {
        int t = __shfl_up(incl, off);
        if (lane >= off) incl += t;
    }
    if (lane == 63) wsum[w] = incl;
    __syncthreads();
    int woff = 0;
    #pragma unroll
    for (int j = 0; j < 16; ++j) woff += (j < w) ? wsum[j] : 0;
    if (i < n) out[i] = woff + (incl - v);
    if (tid == 0) {
        int tot = 0;
        #pragma unroll
        for (int j = 0; j < 16; ++j) tot += wsum[j];
        bsum[blockIdx.x] = tot;
    }
}

__global__ void scanpartials_kernel(int* __restrict__ bsum, int nblk) {
    __shared__ int wsum[16];
    int tid = threadIdx.x;
    int lane = tid & 63;
    int w = tid >> 6;
    int v = (tid < nblk) ? bsum[tid] : 0;
    int incl = v;
    #pragma unroll
    for (int off = 1; off < 64; off <<= 1) {
        int t = __shfl_up(incl, off);
        if (lane >= off) incl += t;
    }
    if (lane == 63) wsum[w] = incl;
    __syncthreads();
    int woff = 0;
    #pragma unroll
    for (int j = 0; j < 16; ++j) woff += (j < w) ? wsum[j] : 0;
    if (tid < nblk) bsum[tid] = woff + (incl - v);
}

__global__ void addoff_kernel(int* __restrict__ out, const int* __restrict__ bsum, int n) {
    int i = blockIdx.x * 1024 + threadIdx.x;
    if (i < n) out[i] += bsum[i >> 10];
    if (i == 0) out[n] = N_EDGES;
}

// ---------------------------------------------------------------- CSR scatter (no atomics)
__global__ void scatter_kernel(const int* __restrict__ src, const int* __restrict__ dst,
                               const int* __restrict__ row_start, const int* __restrict__ pos,
                               int* __restrict__ esrc, int e) {
    int i = blockIdx.x * blockDim.x + threadIdx.x;
    if (i >= e) return;
    __builtin_nontemporal_store(src[i], &esrc[row_start[dst[i]] + pos[i]]);
}

// ---------------------------------------------------------------- convert weights to bf16
__global__ void cvt_w_kernel(const float* __restrict__ W1, const float* __restrict__ W2,
                             ushort* __restrict__ w1bf, ushort* __restrict__ w2bf) {
    int i = blockIdx.x * blockDim.x + threadIdx.x;
    if (i < 64 * 512) w1bf[i] = f2bf(W1[i]);
    if (i < 64 * 64)  w2bf[i] = f2bf(W2[i]);
}

// ---------------------------------------------------------------- fused MFMA MLP -> y0 = dinv*h, g = alpha*dinv*h
__global__ __launch_bounds__(256, 2) void mlp_mfma_kernel(
    const float* __restrict__ x, const ushort* __restrict__ w1bf, const float* __restrict__ b1,
    const ushort* __restrict__ w2bf, const float* __restrict__ b2, const float* __restrict__ dinv,
    ushort* __restrict__ y0, ushort* __restrict__ g, int n)
{
    __shared__ ushort w1s[64 * 512];
    __shared__ ushort w2s[64 * 64];
    __shared__ float  b1s[64], b2s[64];

    int t = threadIdx.x;
    #pragma unroll
    for (int i = 0; i < 16; ++i) {
        int chunk = i * 256 + t;
        int byte = chunk * 16;
        int row = byte >> 10;
        int dst = byte ^ ((row & 7) << 4);
        *reinterpret_cast<uint4*>((char*)w1s + dst) = reinterpret_cast<const uint4*>(w1bf)[chunk];
    }
    #pragma unroll
    for (int i = 0; i < 2; ++i) {
        int chunk = i * 256 + t;
        int byte = chunk * 16;
        int row = byte >> 7;
        int dst = byte ^ ((row & 7) << 4);
        *reinterpret_cast<uint4*>((char*)w2s + dst) = reinterpret_cast<const uint4*>(w2bf)[chunk];
    }
    if (t < 64) { b1s[t] = b1[t]; b2s[t] = b2[t]; }
    __syncthreads();

    int wid = t >> 6;
    int l   = t & 63;
    int lr  = l & 15;
    int lk  = l >> 4;
    int rowbase = blockIdx.x * 256 + wid * 64;

    f32x4 acc[4][4] = {};
    for (int kk = 0; kk < 16; ++kk) {
        int k0 = kk * 32 + lk * 8;
        bf16x8 a[4];
        #pragma unroll
        for (int fr = 0; fr < 4; ++fr) {
            int row = rowbase + fr * 16 + lr;
            row = (row < n) ? row : (n - 1);
            const float* p = x + (size_t)row * F_IN + k0;
            float4 u0 = *reinterpret_cast<const float4*>(p);
            float4 u1 = *reinterpret_cast<const float4*>(p + 4);
            bf16x8 af;
            af[0] = (short)f2bf(u0.x); af[1] = (short)f2bf(u0.y);
            af[2] = (short)f2bf(u0.z); af[3] = (short)f2bf(u0.w);
            af[4] = (short)f2bf(u1.x); af[5] = (short)f2bf(u1.y);
            af[6] = (short)f2bf(u1.z); af[7] = (short)f2bf(u1.w);
            a[fr] = af;
        }
        bf16x8 b[4];
        #pragma unroll
        for (int fc = 0; fc < 4; ++fc) {
            int nn = fc * 16 + lr;
            int byte = nn * 1024 + k0 * 2;
            b[fc] = *reinterpret_cast<const bf16x8*>((char*)w1s + (byte ^ ((nn & 7) << 4)));
        }
        #pragma unroll
        for (int fr = 0; fr < 4; ++fr)
            #pragma unroll
            for (int fc = 0; fc < 4; ++fc)
                acc[fr][fc] = __builtin_amdgcn_mfma_f32_16x16x32_bf16(a[fr], b[fc], acc[fr][fc], 0, 0, 0);
    }

    __syncthreads();
    ushort* h1w = w1s + wid * 4096;
    #pragma unroll
    for (int fr = 0; fr < 4; ++fr) {
        #pragma unroll
        for (int fc = 0; fc < 4; ++fc) {
            #pragma unroll
            for (int reg = 0; reg < 4; ++reg) {
                float v = acc[fr][fc][reg] + b1s[fc * 16 + lr];
                v = fmaxf(v, 0.f);
                int row = fr * 16 + lk * 4 + reg;
                int col = fc * 16 + lr;
                int byte = row * 128 + col * 2;
                *reinterpret_cast<ushort*>((char*)h1w + (byte ^ ((row & 7) << 4))) = f2bf(v);
            }
        }
    }

    f32x4 acc2[4][4] = {};
    #pragma unroll
    for (int kk = 0; kk < 2; ++kk) {
        int k0 = kk * 32 + lk * 8;
        bf16x8 a2[4], bb[4];
        #pragma unroll
        for (int fr = 0; fr < 4; ++fr) {
            int row = fr * 16 + lr;
            int byte = row * 128 + k0 * 2;
            a2[fr] = *reinterpret_cast<const bf16x8*>((char*)h1w + (byte ^ ((row & 7) << 4)));
        }
        #pragma unroll
        for (int fc = 0; fc < 4; ++fc) {
            int nn = fc * 16 + lr;
            int byte = nn * 128 + k0 * 2;
            bb[fc] = *reinterpret_cast<const bf16x8*>((char*)w2s + (byte ^ ((nn & 7) << 4)));
        }
        #pragma unroll
        for (int fr = 0; fr < 4; ++fr)
            #pragma unroll
            for (int fc = 0; fc < 4; ++fc)
                acc2[fr][fc] = __builtin_amdgcn_mfma_f32_16x16x32_bf16(a2[fr], bb[fc], acc2[fr][fc], 0, 0, 0);
    }

    // epilogue: h = acc2 + b2; write y0 = dinv*h, g = alpha*dinv*h
    #pragma unroll
    for (int fr = 0; fr < 4; ++fr) {
        #pragma unroll
        for (int fc = 0; fc < 4; ++fc) {
            #pragma unroll
            for (int reg = 0; reg < 4; ++reg) {
                int row = rowbase + fr * 16 + lk * 4 + reg;
                int col = fc * 16 + lr;
                if (row < n) {
                    float d = dinv[row];
                    float hv = (acc2[fr][fc][reg] + b2s[col]) * d;
                    size_t o = (size_t)row * 64 + col;
                    y0[o] = f2bf(hv);
                    g[o]  = f2bf(ALPHA * hv);
                }
            }
        }
    }
}

// ---------------------------------------------------------------- APPNP step: wave = node, lane = channel
// y' = selfc*(sum_src y[src] + y) + g ;  LAST: fused log_softmax of z = y'/dinv
template<bool LAST>
__global__ __launch_bounds__(256) void appnp_step_kernel(
    const int* __restrict__ rs, const int* __restrict__ esrc,
    const float* __restrict__ selfc, const float* __restrict__ dinv,
    const ushort* __restrict__ yin, const ushort* __restrict__ g,
    ushort* __restrict__ yout, float* __restrict__ lsm, int n)
{
    int idx = blockIdx.x * blockDim.x + threadIdx.x;
    int wid = idx >> 6;
    int lane = idx & 63;
    if (wid >= n) return;
    int beg = rs[wid], end = rs[wid + 1];

    float a0 = 0.f, a1 = 0.f, a2 = 0.f, a3 = 0.f;
    float a4 = 0.f, a5 = 0.f, a6 = 0.f, a7 = 0.f;
    int e = beg;
    for (; e + 7 < end; e += 8) {
        int s0 = esrc[e],     s1 = esrc[e + 1], s2 = esrc[e + 2], s3 = esrc[e + 3];
        int s4 = esrc[e + 4], s5 = esrc[e + 5], s6 = esrc[e + 6], s7 = esrc[e + 7];
        a0 += bf2f(yin[(size_t)s0 * 64 + lane]);
        a1 += bf2f(yin[(size_t)s1 * 64 + lane]);
        a2 += bf2f(yin[(size_t)s2 * 64 + lane]);
        a3 += bf2f(yin[(size_t)s3 * 64 + lane]);
        a4 += bf2f(yin[(size_t)s4 * 64 + lane]);
        a5 += bf2f(yin[(size_t)s5 * 64 + lane]);
        a6 += bf2f(yin[(size_t)s6 * 64 + lane]);
        a7 += bf2f(yin[(size_t)s7 * 64 + lane]);
    }
    for (; e < end; ++e)
        a0 += bf2f(yin[(size_t)esrc[e] * 64 + lane]);
    float sum = ((a0 + a1) + (a2 + a3)) + ((a4 + a5) + (a6 + a7));

    size_t o = (size_t)wid * 64 + lane;
    float yn = selfc[wid] * (sum + bf2f(yin[o])) + bf2f(g[o]);
    if (!LAST) {
        yout[o] = f2bf(yn);
    } else {
        float z = yn / dinv[wid];
        float m = z;
        #pragma unroll
        for (int off = 32; off > 0; off >>= 1) m = fmaxf(m, __shfl_xor(m, off));
        float ex = expf(z - m);
        float s = ex;
        #pragma unroll
        for (int off = 32; off > 0; off >>= 1) s += __shfl_xor(s, off);
        lsm[o] = z - m - logf(s);
    }
}

// ---------------------------------------------------------------- launch
extern "C" void kernel_launch(void* const* d_in, const int* in_sizes, int n_in,
                              void* d_out, int out_size, void* d_ws, size_t ws_size,
                              hipStream_t stream) {
    const float* x  = (const float*)d_in[0];
    const float* W1 = (const float*)d_in[1];
    const float* b1 = (const float*)d_in[2];
    const float* W2 = (const float*)d_in[3];
    const float* b2 = (const float*)d_in[4];
    const int*   ei = (const int*)d_in[5];
    const int* src = ei;
    const int* dst = ei + N_EDGES;
    float* out = (float*)d_out;

    char* ws = (char*)d_ws;
    size_t off = 0;
    auto alloc = [&](size_t bytes) -> void* {
        void* p = ws + off;
        off += (bytes + 255) & ~(size_t)255;
        return p;
    };
    int*    deg       = (int*)   alloc((size_t)N_NODES * 4);
    int*    row_start = (int*)   alloc((size_t)(N_NODES + 1) * 4);
    int*    bsum      = (int*)   alloc((size_t)NBLK * 4);
    float*  dinv      = (float*) alloc((size_t)N_NODES * 4);
    float*  selfc     = (float*) alloc((size_t)N_NODES * 4);
    int*    pos       = (int*)   alloc((size_t)N_EDGES * 4);
    int*    esrc      = (int*)   alloc((size_t)N_EDGES * 4);
    ushort* g         = (ushort*)alloc((size_t)N_NODES * 64 * 2);
    ushort* ya        = (ushort*)alloc((size_t)N_NODES * 64 * 2);
    ushort* yb        = (ushort*)alloc((size_t)N_NODES * 64 * 2);
    ushort* w1bf      = (ushort*)alloc((size_t)H_DIM * F_IN * 2);
    ushort* w2bf      = (ushort*)alloc((size_t)C_DIM * H_DIM * 2);

    zero_kernel<<<(N_NODES + 255) / 256, 256, 0, stream>>>(deg, N_NODES);
    degpos_kernel<<<(N_EDGES + 255) / 256, 256, 0, stream>>>(dst, deg, pos, N_EDGES);
    dinv_kernel<<<(N_NODES + 255) / 256, 256, 0, stream>>>(deg, dinv, selfc, N_NODES);
    blockscan_kernel<<<NBLK, 1024, 0, stream>>>(deg, row_start, bsum, N_NODES);
    scanpartials_kernel<<<1, 1024, 0, stream>>>(bsum, NBLK);
    addoff_kernel<<<NBLK, 1024, 0, stream>>>(row_start, bsum, N_NODES);
    scatter_kernel<<<(N_EDGES + 255) / 256, 256, 0, stream>>>(src, dst, row_start, pos,
                                                              esrc, N_EDGES);
    cvt_w_kernel<<<(H_DIM * F_IN + 255) / 256, 256, 0, stream>>>(W1, W2, w1bf, w2bf);
    mlp_mfma_kernel<<<(N_NODES + 255) / 256, 256, 0, stream>>>(x, w1bf, b1, w2bf, b2, dinv,
                                                               ya, g, N_NODES);

    const int grid = (N_NODES * 64 + 255) / 256;
    ushort* yin = ya;
    ushort* yout = yb;
    for (int k = 0; k < K_STEPS - 1; ++k) {
        appnp_step_kernel<false><<<grid, 256, 0, stream>>>(
            row_start, esrc, selfc, dinv, yin, g, yout, nullptr, N_NODES);
        ushort* tmp = yin; yin = yout; yout = tmp;
    }
    appnp_step_kernel<true><<<grid, 256, 0, stream>>>(
        row_start, esrc, selfc, dinv, yin, g, nullptr, out, N_NODES);
}